// Round 1
// baseline (4863.002 us; speedup 1.0000x reference)
//
#include <hip/hip_runtime.h>
#include <hip/hip_bf16.h>

// LSTM recurrence: T=512, B=64, D=H=1024, gates 4H=4096.
// R4: batch-partitioned groups. The recurrence is independent per batch
// sample (h(t+1)[b] depends only on h(t)[b]); only Wh reuse couples blocks.
//   - 4 independent groups x 64 blocks; group g owns batches 16g..16g+15.
//     Barrier fan-in 256 -> 64 (1 flag load/lane), groups free-run.
//   - Block = 16 batches x 64 gate-cols, FULL K=1024 per wave (4 waves,
//     each 16 gate-cols). Wh slice held ENTIRELY in VGPRs (32 frag8/lane,
//     128 VGPR); zero LDS in the step loop, no cross-wave reduction.
//   - Gates gathered via 16 intra-wave shfls; elementwise on all 64 lanes
//     (1 creg/lane).
//   - Sync protocol unchanged from R3 (proven): sc0sc1 write-through h to
//     fresh ring slot + vmcnt(0) + relaxed flag store; readers use plain
//     cached loads on fresh addresses.
//   - xg precomputed TRANSPOSED [4096][M]; per-lane float4 read/step.

#define T_STEPS  512
#define BATCH    64
#define DIM      1024
#define NG       4096
#define NBLK     256
#define PTHREADS 256
#define GBLK     64      // blocks per group
#define GB       16      // batches per group
// ring slot: 64*1024 bf16 + 4KB pad (guards against any line prefetch)
#define HSLOT    ((size_t)(BATCH * DIM + 2048))

typedef __attribute__((ext_vector_type(8))) short frag8;   // 8 x bf16
typedef __attribute__((ext_vector_type(4))) float f32x4;

__device__ __forceinline__ short f2bf(float f) {
    union { float f; unsigned u; } v; v.f = f;
    unsigned r = v.u + 0x7fffu + ((v.u >> 16) & 1u);   // RNE
    return (short)(r >> 16);
}
__device__ __forceinline__ float sigm(float x) { return 1.0f / (1.0f + __expf(-x)); }
__device__ __forceinline__ float tanh_fast(float x) { return 1.0f - 2.0f / (__expf(2.0f * x) + 1.0f); }

// ---------------- prep kernels ----------------

__global__ __launch_bounds__(256)
void cast_transpose(const float* __restrict__ W, short* __restrict__ WT) {
    __shared__ float tile[32][33];
    int k0 = blockIdx.x * 32;
    int n0 = blockIdx.y * 32;
    int tx = threadIdx.x & 31, ty = threadIdx.x >> 5;
    #pragma unroll
    for (int i = 0; i < 32; i += 8)
        tile[ty + i][tx] = W[(size_t)(k0 + ty + i) * NG + n0 + tx];
    __syncthreads();
    #pragma unroll
    for (int i = 0; i < 32; i += 8)
        WT[(size_t)(n0 + ty + i) * DIM + k0 + tx] = f2bf(tile[tx][ty + i]);
}

__global__ __launch_bounds__(256)
void init_state(const float* __restrict__ c0, const float* __restrict__ h0,
                float* __restrict__ c, short* __restrict__ hring,
                unsigned* __restrict__ flags) {
    int i = blockIdx.x * 256 + threadIdx.x;     // 65536 threads
    c[i] = c0[i];
    hring[i] = f2bf(h0[i]);                     // slot 0
    if (i < NBLK * 32) flags[i] = 0u;
}

__global__ __launch_bounds__(256)
void xcast(const float* __restrict__ x, short* __restrict__ xb, int n8) {
    int i = blockIdx.x * 256 + threadIdx.x;
    if (i >= n8) return;
    const float4* p = (const float4*)(x + (size_t)i * 8);
    float4 a = p[0], b = p[1];
    frag8 v;
    v[0] = f2bf(a.x); v[1] = f2bf(a.y); v[2] = f2bf(a.z); v[3] = f2bf(a.w);
    v[4] = f2bf(b.x); v[5] = f2bf(b.y); v[6] = f2bf(b.z); v[7] = f2bf(b.w);
    *(frag8*)(xb + (size_t)i * 8) = v;
}

// xg^T[N=4096][M] = (A[M][1024] @ Wi)^T.  128x128 tile, BK=32, transposed store.
__global__ __launch_bounds__(256)
void xgemm(const short* __restrict__ A, const short* __restrict__ B,
           float* __restrict__ CT_, int M) {
    __shared__ short As[4096];
    __shared__ short Bs[4096];
    const int tid = threadIdx.x;
    const int w = tid >> 6, l = tid & 63, m = l & 15, q = l >> 4;
    const size_t abase = (size_t)blockIdx.x * 128 * DIM;
    const size_t bbase = (size_t)blockIdx.y * 128 * DIM;

    f32x4 acc[2][8];
    #pragma unroll
    for (int i = 0; i < 2; ++i)
        #pragma unroll
        for (int j = 0; j < 8; ++j) acc[i][j] = (f32x4){0.f, 0.f, 0.f, 0.f};

    for (int kc = 0; kc < 32; ++kc) {
        #pragma unroll
        for (int c2 = 0; c2 < 2; ++c2) {
            int t2 = c2 * 256 + tid;
            int seg = t2 >> 7, row = t2 & 127;
            const short* ga = A + abase + (size_t)row * DIM + kc * 32 + seg * 8;
            const short* gb = B + bbase + (size_t)row * DIM + kc * 32 + seg * 8;
            __builtin_amdgcn_global_load_lds(
                (const __attribute__((address_space(1))) void*)ga,
                (__attribute__((address_space(3))) void*)(As + t2 * 8), 16, 0, 0);
            __builtin_amdgcn_global_load_lds(
                (const __attribute__((address_space(1))) void*)gb,
                (__attribute__((address_space(3))) void*)(Bs + t2 * 8), 16, 0, 0);
        }
        __syncthreads();
        frag8 a0 = *(const frag8*)(As + (q * 128 + w * 32 + m) * 8);
        frag8 a1 = *(const frag8*)(As + (q * 128 + w * 32 + 16 + m) * 8);
        #pragma unroll
        for (int nt = 0; nt < 8; ++nt) {
            frag8 bf = *(const frag8*)(Bs + (q * 128 + nt * 16 + m) * 8);
            acc[0][nt] = __builtin_amdgcn_mfma_f32_16x16x32_bf16(a0, bf, acc[0][nt], 0, 0, 0);
            acc[1][nt] = __builtin_amdgcn_mfma_f32_16x16x32_bf16(a1, bf, acc[1][nt], 0, 0, 0);
        }
        __syncthreads();
    }
    // transposed store: CT_[col][row], 16B contiguous per lane
    #pragma unroll
    for (int mt = 0; mt < 2; ++mt)
        #pragma unroll
        for (int nt = 0; nt < 8; ++nt) {
            int row0 = blockIdx.x * 128 + w * 32 + mt * 16 + q * 4;
            int col  = blockIdx.y * 128 + nt * 16 + m;
            *(float4*)(CT_ + (size_t)col * M + row0) =
                make_float4(acc[mt][nt][0], acc[mt][nt][1], acc[mt][nt][2], acc[mt][nt][3]);
        }
}

// ---------------- persistent recurrence ----------------
// Block b: grp = b>>6 (batches 16*grp..+15), kblk = b&63 (h-cols 16*kblk..+15).
// 4 waves x 16 gate-cols (4 h-cols x 4 gates), full K per wave, Wh in VGPRs.
__global__ __launch_bounds__(PTHREADS, 1)
void lstm_persist(const float* __restrict__ xgT,    // [4096][M] f32
                  const short* __restrict__ WhT,    // [4096][1024] bf16
                  const float* __restrict__ bias,
                  float* __restrict__ cstate,       // [64][1024] f32
                  short* __restrict__ hring,        // CT slots of HSLOT
                  float* __restrict__ y,            // out + chunk offset
                  unsigned* __restrict__ flags,     // NBLK x 32 uints (128B pad)
                  int gstep0, int CTC, int M) {
    const int tid = threadIdx.x;
    const int w = tid >> 6, l = tid & 63;            // wave = col-tile
    const int m = l & 15, q4 = l >> 4;
    const int grp  = blockIdx.x >> 6;                // batch group
    const int kblk = blockIdx.x & 63;                // col block within group
    const int j0w  = kblk * 16 + w * 4;              // this wave's 4 h-cols
    // lane's gate-col in MFMA B layout (cc = m): gate m>>2, col-ofs m&3
    const int gcol = (m >> 2) * DIM + j0w + (m & 3);

    // Wh slice -> registers: 32 frag8 per lane (128 VGPR), statically indexed
    frag8 wreg[32];
    #pragma unroll
    for (int kc = 0; kc < 32; ++kc)
        wreg[kc] = *(const frag8*)(WhT + (size_t)gcol * DIM + kc * 32 + q4 * 8);

    // elementwise identity of this lane: batch = l>>2, col-ofs = l&3
    const int eb = grp * GB + (l >> 2);              // global batch
    const int ec = j0w + (l & 3);                    // global h-col
    float creg = cstate[(size_t)eb * DIM + ec];
    const float bv = bias[gcol];                     // per-lane gate bias

    const int rsel  = (l >> 2) & 3;                  // source MFMA reg
    const int sbase = (l & 48) + (l & 3);            // source lane base

    for (int t = 0; t < CTC; ++t) {
        // prefetch gate inputs (chunk-static, hidden under the poll)
        const float4 xv = *(const float4*)(
            xgT + (size_t)gcol * M + (size_t)t * BATCH + grp * GB + q4 * 4);

        // wait for this group's 64 producers (skip t=0: init/prev launch)
        if (t > 0 && w == 0) {
            const unsigned target = (unsigned)(gstep0 + t);
            const unsigned* fp = &flags[(grp * GBLK + l) * 32];
            for (;;) {
                unsigned f = __hip_atomic_load(fp, __ATOMIC_RELAXED,
                                               __HIP_MEMORY_SCOPE_AGENT);
                if (__all(f >= target)) break;
                __builtin_amdgcn_s_sleep(2);
            }
        }
        __syncthreads();

        // h(t)[group batches] @ Wh cols, full K=1024
        const short* hrow = hring + (size_t)t * HSLOT
                          + (size_t)(grp * GB + m) * DIM;
        f32x4 acc = {0.f, 0.f, 0.f, 0.f};
        #pragma unroll
        for (int kc = 0; kc < 32; ++kc) {
            frag8 a = *(const frag8*)(hrow + kc * 32 + q4 * 8);
            acc = __builtin_amdgcn_mfma_f32_16x16x32_bf16(a, wreg[kc], acc, 0, 0, 0);
        }
        // pre-activations (lane: gate m>>2, col m&3, batches q4*4+r)
        acc[0] += xv.x + bv; acc[1] += xv.y + bv;
        acc[2] += xv.z + bv; acc[3] += xv.w + bv;

        // gather the 4 gates to lane p=(b<<2)|ej from lane (p&48)+g*4+(p&3),
        // reg (p>>2)&3 — all intra-16-lane-group shuffles
        float pre[4];
        #pragma unroll
        for (int g = 0; g < 4; ++g) {
            const int src = sbase + g * 4;
            float t0 = __shfl(acc[0], src);
            float t1 = __shfl(acc[1], src);
            float t2 = __shfl(acc[2], src);
            float t3 = __shfl(acc[3], src);
            pre[g] = rsel == 0 ? t0 : rsel == 1 ? t1 : rsel == 2 ? t2 : t3;
        }
        const float gi = sigm(pre[0]);
        const float gf = sigm(pre[1]);
        const float gg = tanh_fast(pre[2]);
        const float go = sigm(pre[3]);
        creg = gf * creg + gi * gg;
        const float hn = go * tanh_fast(creg);

        // pack 4 cols of one batch -> float4 y store + 8B h write-through
        const float y1 = __shfl_down(hn, 1), y2 = __shfl_down(hn, 2), y3 = __shfl_down(hn, 3);
        unsigned hb0 = (unsigned)(unsigned short)f2bf(hn);
        unsigned hb1 = __shfl_down(hb0, 1);
        unsigned hb2 = __shfl_down(hb0, 2);
        unsigned hb3 = __shfl_down(hb0, 3);
        if ((l & 3) == 0) {
            *(float4*)(y + ((size_t)t * BATCH + eb) * DIM + j0w) =
                make_float4(hn, y1, y2, y3);
            const int dslot = (t == CTC - 1) ? 0 : (t + 1);
            unsigned long long v = (unsigned long long)(hb0 | (hb1 << 16))
                                 | ((unsigned long long)(hb2 | (hb3 << 16)) << 32);
            __hip_atomic_store(
                (unsigned long long*)(hring + (size_t)dslot * HSLOT
                                      + (size_t)eb * DIM + j0w),
                v, __ATOMIC_RELAXED, __HIP_MEMORY_SCOPE_AGENT);
        }

        if (t < CTC - 1) {
            // drain write-through stores to the coherence point, then signal
            asm volatile("s_waitcnt vmcnt(0)" ::: "memory");
            __syncthreads();
            if (tid == 0)
                __hip_atomic_store(&flags[blockIdx.x * 32], (unsigned)(gstep0 + t + 1),
                                   __ATOMIC_RELAXED, __HIP_MEMORY_SCOPE_AGENT);
        }
    }
    cstate[(size_t)eb * DIM + ec] = creg;
}

// ---------------- host ----------------
extern "C" void kernel_launch(void* const* d_in, const int* in_sizes, int n_in,
                              void* d_out, int out_size, void* d_ws, size_t ws_size,
                              hipStream_t stream) {
    const float* x  = (const float*)d_in[0];
    const float* c0 = (const float*)d_in[1];
    const float* h0 = (const float*)d_in[2];
    const float* Wi = (const float*)d_in[3];
    const float* Wh = (const float*)d_in[4];
    const float* b  = (const float*)d_in[5];
    float* out = (float*)d_out;

    char* ws = (char*)d_ws;
    short*    WiT   = (short*)(ws);                    // 8 MB
    short*    WhT   = (short*)(ws + 8388608);          // 8 MB
    float*    c     = (float*)(ws + 16777216);         // 256 KB
    unsigned* flags = (unsigned*)(ws + 17039360);      // 32 KB (256 x 128B)
    const size_t fixed = 17072128;

    // per-CT bytes: hring CT*HSLOT*2 + xbf CT*128KB + xgT CT*1MB
    const size_t perCT = HSLOT * 2 + 131072 + 1048576;   // 1,314,816
    int CT = 2;
    const int cands[9] = {512, 256, 128, 64, 32, 16, 8, 4, 2};
    for (int i = 0; i < 9; ++i)
        if (fixed + (size_t)cands[i] * perCT <= ws_size) { CT = cands[i]; break; }

    short* hring = (short*)(ws + fixed);
    short* xbf   = (short*)(ws + fixed + (size_t)CT * HSLOT * 2);
    float* xgT   = (float*)(ws + fixed + (size_t)CT * (HSLOT * 2 + 131072));
    const int M = CT * BATCH;

    cast_transpose<<<dim3(DIM / 32, NG / 32), 256, 0, stream>>>(Wi, WiT);
    cast_transpose<<<dim3(DIM / 32, NG / 32), 256, 0, stream>>>(Wh, WhT);
    init_state<<<dim3(BATCH * DIM / 256), 256, 0, stream>>>(c0, h0, c, hring, flags);

    const int nchunks = T_STEPS / CT;
    for (int ch = 0; ch < nchunks; ++ch) {
        const size_t xoff = (size_t)ch * CT * BATCH * DIM;
        const int n8 = CT * BATCH * DIM / 8;
        xcast<<<dim3((n8 + 255) / 256), 256, 0, stream>>>(x + xoff, xbf, n8);
        xgemm<<<dim3(M / 128, NG / 128), 256, 0, stream>>>(xbf, WiT, xgT, M);
        lstm_persist<<<dim3(NBLK), PTHREADS, 0, stream>>>(
            xgT, WhT, b, c, hring, out + xoff, flags, ch * CT, CT, M);
    }
}

// Round 2
// 4129.797 us; speedup vs baseline: 1.1775x; 1.1775x over previous
//
#include <hip/hip_runtime.h>
#include <hip/hip_bf16.h>

// LSTM recurrence: T=512, B=64, D=H=1024, gates 4H=4096.
// R5: R3's proven compute engine + R4's batch-group partition.
//   - 4 independent groups x 64 blocks; group g owns batches 16g..16g+15.
//     Poll fan-in 64 (1 flag load/lane); groups free-run.
//   - Block = 16 batches x 64 gate-cols (16 h-cols). Wh slice in 128 KB
//     STATIC LDS (gfx950 allows 160 KB; avoids R4's VGPR-remat disaster).
//   - 8 waves = 4 col-groups x 2 K-halves, 16 MFMAs/wave (M=16 full),
//     partials reduced through LDS (R3 pattern).
//   - y-store moved AFTER the flag signal: vmcnt(0) no longer drains the
//     HBM y-store ack on the critical path (only the 8B h write-throughs).
//   - Sync protocol otherwise unchanged (proven): sc0sc1 write-through h
//     to fresh ring slot + vmcnt(0) + relaxed flag; readers plain loads.

#define T_STEPS  512
#define BATCH    64
#define DIM      1024
#define NG       4096
#define NBLK     256
#define PTHREADS 512
#define NGRP     4
#define GBLK     64      // blocks per group
#define GB       16      // batches per group
// ring slot: 64*1024 bf16 + 4KB pad (guards against any line prefetch)
#define HSLOT    ((size_t)(BATCH * DIM + 2048))

typedef __attribute__((ext_vector_type(8))) short frag8;   // 8 x bf16
typedef __attribute__((ext_vector_type(4))) float f32x4;

__device__ __forceinline__ short f2bf(float f) {
    union { float f; unsigned u; } v; v.f = f;
    unsigned r = v.u + 0x7fffu + ((v.u >> 16) & 1u);   // RNE
    return (short)(r >> 16);
}
__device__ __forceinline__ float sigm(float x) { return 1.0f / (1.0f + __expf(-x)); }
__device__ __forceinline__ float tanh_fast(float x) { return 1.0f - 2.0f / (__expf(2.0f * x) + 1.0f); }

// ---------------- prep kernels ----------------

__global__ __launch_bounds__(256)
void cast_transpose(const float* __restrict__ W, short* __restrict__ WT) {
    __shared__ float tile[32][33];
    int k0 = blockIdx.x * 32;
    int n0 = blockIdx.y * 32;
    int tx = threadIdx.x & 31, ty = threadIdx.x >> 5;
    #pragma unroll
    for (int i = 0; i < 32; i += 8)
        tile[ty + i][tx] = W[(size_t)(k0 + ty + i) * NG + n0 + tx];
    __syncthreads();
    #pragma unroll
    for (int i = 0; i < 32; i += 8)
        WT[(size_t)(n0 + ty + i) * DIM + k0 + tx] = f2bf(tile[tx][ty + i]);
}

__global__ __launch_bounds__(256)
void init_state(const float* __restrict__ c0, const float* __restrict__ h0,
                float* __restrict__ c, short* __restrict__ hring,
                unsigned* __restrict__ flags) {
    int i = blockIdx.x * 256 + threadIdx.x;     // 65536 threads
    c[i] = c0[i];
    hring[i] = f2bf(h0[i]);                     // slot 0
    if (i < NBLK * 32) flags[i] = 0u;
}

__global__ __launch_bounds__(256)
void xcast(const float* __restrict__ x, short* __restrict__ xb, int n8) {
    int i = blockIdx.x * 256 + threadIdx.x;
    if (i >= n8) return;
    const float4* p = (const float4*)(x + (size_t)i * 8);
    float4 a = p[0], b = p[1];
    frag8 v;
    v[0] = f2bf(a.x); v[1] = f2bf(a.y); v[2] = f2bf(a.z); v[3] = f2bf(a.w);
    v[4] = f2bf(b.x); v[5] = f2bf(b.y); v[6] = f2bf(b.z); v[7] = f2bf(b.w);
    *(frag8*)(xb + (size_t)i * 8) = v;
}

// xg^T[N=4096][M] = (A[M][1024] @ Wi)^T.  128x128 tile, BK=32, transposed store.
__global__ __launch_bounds__(256)
void xgemm(const short* __restrict__ A, const short* __restrict__ B,
           float* __restrict__ CT_, int M) {
    __shared__ short As[4096];
    __shared__ short Bs[4096];
    const int tid = threadIdx.x;
    const int w = tid >> 6, l = tid & 63, m = l & 15, q = l >> 4;
    const size_t abase = (size_t)blockIdx.x * 128 * DIM;
    const size_t bbase = (size_t)blockIdx.y * 128 * DIM;

    f32x4 acc[2][8];
    #pragma unroll
    for (int i = 0; i < 2; ++i)
        #pragma unroll
        for (int j = 0; j < 8; ++j) acc[i][j] = (f32x4){0.f, 0.f, 0.f, 0.f};

    for (int kc = 0; kc < 32; ++kc) {
        #pragma unroll
        for (int c2 = 0; c2 < 2; ++c2) {
            int t2 = c2 * 256 + tid;
            int seg = t2 >> 7, row = t2 & 127;
            const short* ga = A + abase + (size_t)row * DIM + kc * 32 + seg * 8;
            const short* gb = B + bbase + (size_t)row * DIM + kc * 32 + seg * 8;
            __builtin_amdgcn_global_load_lds(
                (const __attribute__((address_space(1))) void*)ga,
                (__attribute__((address_space(3))) void*)(As + t2 * 8), 16, 0, 0);
            __builtin_amdgcn_global_load_lds(
                (const __attribute__((address_space(1))) void*)gb,
                (__attribute__((address_space(3))) void*)(Bs + t2 * 8), 16, 0, 0);
        }
        __syncthreads();
        frag8 a0 = *(const frag8*)(As + (q * 128 + w * 32 + m) * 8);
        frag8 a1 = *(const frag8*)(As + (q * 128 + w * 32 + 16 + m) * 8);
        #pragma unroll
        for (int nt = 0; nt < 8; ++nt) {
            frag8 bf = *(const frag8*)(Bs + (q * 128 + nt * 16 + m) * 8);
            acc[0][nt] = __builtin_amdgcn_mfma_f32_16x16x32_bf16(a0, bf, acc[0][nt], 0, 0, 0);
            acc[1][nt] = __builtin_amdgcn_mfma_f32_16x16x32_bf16(a1, bf, acc[1][nt], 0, 0, 0);
        }
        __syncthreads();
    }
    // transposed store: CT_[col][row], 16B contiguous per lane
    #pragma unroll
    for (int mt = 0; mt < 2; ++mt)
        #pragma unroll
        for (int nt = 0; nt < 8; ++nt) {
            int row0 = blockIdx.x * 128 + w * 32 + mt * 16 + q * 4;
            int col  = blockIdx.y * 128 + nt * 16 + m;
            *(float4*)(CT_ + (size_t)col * M + row0) =
                make_float4(acc[mt][nt][0], acc[mt][nt][1], acc[mt][nt][2], acc[mt][nt][3]);
        }
}

// ---------------- persistent recurrence ----------------
// Block b: grp = b>>6 (batches 16*grp..+15), kblk = b&63 (h-cols 16*kblk..+15).
// 8 waves: cg = w&3 (4 h-cols -> 16 gate-cols), kh = w>>2 (K half).
// Wh slice (64 gate-cols x 1024) staged in 128 KB LDS.
__global__ __launch_bounds__(PTHREADS, 1)
void lstm_persist(const float* __restrict__ xgT,    // [4096][M] f32
                  const short* __restrict__ WhT,    // [4096][1024] bf16
                  const float* __restrict__ bias,
                  float* __restrict__ cstate,       // [64][1024] f32
                  short* __restrict__ hring,        // CT slots of HSLOT
                  float* __restrict__ y,            // out + chunk offset
                  unsigned* __restrict__ flags,     // NBLK x 32 uints (128B pad)
                  int gstep0, int CTC, int M) {
    __shared__ short whs[4 * 32 * 64 * 8];   // 128 KB: [cg][kidx0..31][lane][8]
    __shared__ float gsm2[2][16][68];        // partials [kh][batch][gate*16+hcol]
    const int tid = threadIdx.x;
    const int w = tid >> 6, l = tid & 63, m = l & 15, q4 = l >> 4;
    const int cg = w & 3, kh = w >> 2;
    const int grp  = blockIdx.x >> 6;                // batch group
    const int kblk = blockIdx.x & 63;                // col block within group
    const int j0   = kblk * 16;                      // 16 h-cols

    // stage Wh: [scg][kidx][lane(cc,qq)][8]; col cc -> gate cc>>2, ofs cc&3
    for (int idx = tid; idx < 4 * 32 * 64; idx += PTHREADS) {
        int scg = idx >> 11, rem = idx & 2047;
        int kcc = rem >> 6, ll = rem & 63, cc = ll & 15, qq = ll >> 4;
        int gcol = (cc >> 2) * DIM + j0 + scg * 4 + (cc & 3);
        *(frag8*)(whs + idx * 8) =
            *(const frag8*)(WhT + (size_t)gcol * DIM + kcc * 32 + qq * 8);
    }

    // elementwise identity (tid < 256): bl = l&15 (batch), jl = w*4+q4 (h-col)
    const int bl = l & 15;
    const int jl = w * 4 + q4;                       // valid when tid<256
    const int eb = grp * GB + bl;                    // global batch
    const int ec = j0 + jl;                          // global h-col
    float creg = 0.f, bv0 = 0.f, bv1 = 0.f, bv2 = 0.f, bv3 = 0.f;
    if (tid < 256) {
        creg = cstate[(size_t)eb * DIM + ec];
        bv0 = bias[0 * DIM + ec];
        bv1 = bias[1 * DIM + ec];
        bv2 = bias[2 * DIM + ec];
        bv3 = bias[3 * DIM + ec];
    }
    __syncthreads();

    for (int t = 0; t < CTC; ++t) {
        // prefetch gate inputs (chunk-static, hidden under the poll)
        float xv0 = 0.f, xv1 = 0.f, xv2 = 0.f, xv3 = 0.f;
        if (tid < 256) {
            const size_t r = (size_t)t * BATCH + eb;
            xv0 = xgT[(size_t)(0 * DIM + ec) * M + r];
            xv1 = xgT[(size_t)(1 * DIM + ec) * M + r];
            xv2 = xgT[(size_t)(2 * DIM + ec) * M + r];
            xv3 = xgT[(size_t)(3 * DIM + ec) * M + r];
        }

        // wait for this group's 64 producers (skip t=0: init/prev launch)
        if (t > 0 && w == 0) {
            const unsigned target = (unsigned)(gstep0 + t);
            const unsigned* fp = &flags[(grp * GBLK + l) * 32];
            for (;;) {
                unsigned f = __hip_atomic_load(fp, __ATOMIC_RELAXED,
                                               __HIP_MEMORY_SCOPE_AGENT);
                if (__all(f >= target)) break;
                __builtin_amdgcn_s_sleep(1);
            }
        }
        __syncthreads();   // gates h reads below (also orders gsm2 reuse)

        // h(t)[group batches] @ Wh cols, K-half per wave
        const short* hrow = hring + (size_t)t * HSLOT
                          + (size_t)(grp * GB + m) * DIM + kh * 512;
        f32x4 acc = {0.f, 0.f, 0.f, 0.f};
        #pragma unroll
        for (int kc = 0; kc < 16; ++kc) {
            frag8 a = *(const frag8*)(hrow + kc * 32 + q4 * 8);
            frag8 b = *(const frag8*)(whs + ((cg * 32 + kh * 16 + kc) * 64 + l) * 8);
            acc = __builtin_amdgcn_mfma_f32_16x16x32_bf16(a, b, acc, 0, 0, 0);
        }
        #pragma unroll
        for (int r = 0; r < 4; ++r)
            gsm2[kh][q4 * 4 + r][(m >> 2) * 16 + cg * 4 + (m & 3)] = acc[r];
        __syncthreads();

        float hn = 0.f, ya = 0.f, yb = 0.f, yc = 0.f;
        unsigned long long hv = 0ull;
        if (tid < 256) {
            const float gi = sigm(     gsm2[0][bl][ 0 + jl] + gsm2[1][bl][ 0 + jl] + xv0 + bv0);
            const float gf = sigm(     gsm2[0][bl][16 + jl] + gsm2[1][bl][16 + jl] + xv1 + bv1);
            const float gg = tanh_fast(gsm2[0][bl][32 + jl] + gsm2[1][bl][32 + jl] + xv2 + bv2);
            const float go = sigm(     gsm2[0][bl][48 + jl] + gsm2[1][bl][48 + jl] + xv3 + bv3);
            creg = gf * creg + gi * gg;
            hn = go * tanh_fast(creg);

            // pack cols w*4..w*4+3 of batch bl from lanes bl+{0,16,32,48}
            ya = __shfl(hn, bl + 16);
            yb = __shfl(hn, bl + 32);
            yc = __shfl(hn, bl + 48);
            unsigned hb0 = (unsigned)(unsigned short)f2bf(hn);
            unsigned hb1 = __shfl(hb0, bl + 16);
            unsigned hb2 = __shfl(hb0, bl + 32);
            unsigned hb3 = __shfl(hb0, bl + 48);
            if (l < 16) {
                const int dslot = (t == CTC - 1) ? 0 : (t + 1);
                hv = (unsigned long long)(hb0 | (hb1 << 16))
                   | ((unsigned long long)(hb2 | (hb3 << 16)) << 32);
                __hip_atomic_store(
                    (unsigned long long*)(hring + (size_t)dslot * HSLOT
                                          + (size_t)eb * DIM + j0 + w * 4),
                    hv, __ATOMIC_RELAXED, __HIP_MEMORY_SCOPE_AGENT);
            }
        }

        if (t < CTC - 1) {
            // drain ONLY the h write-throughs, then signal
            asm volatile("s_waitcnt vmcnt(0)" ::: "memory");
            __syncthreads();
            if (tid == 0)
                __hip_atomic_store(&flags[blockIdx.x * 32], (unsigned)(gstep0 + t + 1),
                                   __ATOMIC_RELAXED, __HIP_MEMORY_SCOPE_AGENT);
        }

        // y-store AFTER the signal: off the critical path
        if (tid < 256 && l < 16)
            *(float4*)(y + ((size_t)t * BATCH + eb) * DIM + j0 + w * 4) =
                make_float4(hn, ya, yb, yc);
    }
    if (tid < 256) cstate[(size_t)eb * DIM + ec] = creg;
}

// ---------------- host ----------------
extern "C" void kernel_launch(void* const* d_in, const int* in_sizes, int n_in,
                              void* d_out, int out_size, void* d_ws, size_t ws_size,
                              hipStream_t stream) {
    const float* x  = (const float*)d_in[0];
    const float* c0 = (const float*)d_in[1];
    const float* h0 = (const float*)d_in[2];
    const float* Wi = (const float*)d_in[3];
    const float* Wh = (const float*)d_in[4];
    const float* b  = (const float*)d_in[5];
    float* out = (float*)d_out;

    char* ws = (char*)d_ws;
    short*    WiT   = (short*)(ws);                    // 8 MB
    short*    WhT   = (short*)(ws + 8388608);          // 8 MB
    float*    c     = (float*)(ws + 16777216);         // 256 KB
    unsigned* flags = (unsigned*)(ws + 17039360);      // 32 KB (256 x 128B)
    const size_t fixed = 17072128;

    // per-CT bytes: hring CT*HSLOT*2 + xbf CT*128KB + xgT CT*1MB
    const size_t perCT = HSLOT * 2 + 131072 + 1048576;   // 1,314,816
    int CT = 2;
    const int cands[9] = {512, 256, 128, 64, 32, 16, 8, 4, 2};
    for (int i = 0; i < 9; ++i)
        if (fixed + (size_t)cands[i] * perCT <= ws_size) { CT = cands[i]; break; }

    short* hring = (short*)(ws + fixed);
    short* xbf   = (short*)(ws + fixed + (size_t)CT * HSLOT * 2);
    float* xgT   = (float*)(ws + fixed + (size_t)CT * (HSLOT * 2 + 131072));
    const int M = CT * BATCH;

    cast_transpose<<<dim3(DIM / 32, NG / 32), 256, 0, stream>>>(Wi, WiT);
    cast_transpose<<<dim3(DIM / 32, NG / 32), 256, 0, stream>>>(Wh, WhT);
    init_state<<<dim3(BATCH * DIM / 256), 256, 0, stream>>>(c0, h0, c, hring, flags);

    const int nchunks = T_STEPS / CT;
    for (int ch = 0; ch < nchunks; ++ch) {
        const size_t xoff = (size_t)ch * CT * BATCH * DIM;
        const int n8 = CT * BATCH * DIM / 8;
        xcast<<<dim3((n8 + 255) / 256), 256, 0, stream>>>(x + xoff, xbf, n8);
        xgemm<<<dim3(M / 128, NG / 128), 256, 0, stream>>>(xbf, WiT, xgT, M);
        lstm_persist<<<dim3(NBLK), PTHREADS, 0, stream>>>(
            xgT, WhT, b, c, hring, out + xoff, flags, ch * CT, CT, M);
    }
}